// Round 9
// baseline (16599.136 us; speedup 1.0000x reference)
//
#include <hip/hip_runtime.h>

typedef _Float16 f16x8 __attribute__((ext_vector_type(8)));
typedef float f32x4 __attribute__((ext_vector_type(4)));

constexpr int S_ = 128;
constexpr int NRB = 4;                 // real rows per block (12 dummy MFMA rows)
constexpr float DT_ = 0.1f;
constexpr float LS = 2048.0f;          // lo-term scale (2^11) keeps fp16 lo parts normal
constexpr float INV = 1.0f / 2048.0f;

#define MFMA(a, b, c) __builtin_amdgcn_mfma_f32_16x16x32_f16((a), (b), (c), 0, 0, 0)

// bias LDS offsets (floats)
#define OB0   0
#define OB1   256
#define OB2   512
#define OBHH0 640
#define OBIH0 1024
#define OBIH1 1408
#define OBHH1 1792
#define NBIAS 2176

__device__ __forceinline__ float fast_tanh(float x) {
    float e = __expf(2.0f * x);
    return 1.0f - 2.0f / (e + 1.0f);
}
__device__ __forceinline__ float fast_sigmoid(float x) {
    return 1.0f / (1.0f + __expf(-x));
}
__device__ __forceinline__ f32x4 bc4(float v) { return (f32x4){v, v, v, v}; }

// fp32 row-major KxN -> fp16 hi/lo MFMA-B-fragment blobs.
// Tile (nt,kt) at ((nt*KT)+kt)*512; elem lane*8+j <-> B[kt*32+(lane>>4)*8+j][nt*16+(lane&15)].
__global__ void prep_hl(const float* __restrict__ src, _Float16* __restrict__ hi,
                        _Float16* __restrict__ lo, int K, int N) {
    int e = blockIdx.x * 256 + threadIdx.x;
    if (e >= K * N) return;
    int tile = e >> 9, r = e & 511;
    int lane = r >> 3, j = r & 7;
    int KT = K >> 5;
    int nt = tile / KT, kt = tile - nt * KT;
    int k = kt * 32 + ((lane >> 4) << 3) + j;
    int n = nt * 16 + (lane & 15);
    float v = src[k * N + n];
    _Float16 h = (_Float16)v;
    hi[e] = h;
    lo[e] = (_Float16)((v - (float)h) * LS);
}

// One full 16-col n-tile: load 2*KT B-fragments (hi/lo), run 3*KT MFMAs,
// return combined f32x4 = acc + (pe+qe)/LS.
template<int KT>
__device__ __forceinline__ f32x4 tile_mm(
    const _Float16* __restrict__ Wh, const _Float16* __restrict__ Wl, int nt,
    const _Float16* __restrict__ Ah, const _Float16* __restrict__ Al, int lda,
    int l, int lrow, int lk8, float bias)
{
    const _Float16* ph = Wh + ((size_t)nt * KT) * 512 + l * 8;
    const _Float16* pl = Wl + ((size_t)nt * KT) * 512 + l * 8;
    f16x8 bh[KT], bl[KT];
#pragma unroll
    for (int kt = 0; kt < KT; ++kt) {
        bh[kt] = *(const f16x8*)(ph + kt * 512);
        bl[kt] = *(const f16x8*)(pl + kt * 512);
    }
    f32x4 acc = bc4(bias), pe = bc4(0.f), qe = bc4(0.f);
#pragma unroll
    for (int kt = 0; kt < KT; ++kt) {
        f16x8 ah = *(const f16x8*)(Ah + lrow * lda + kt * 32 + lk8);
        f16x8 al = *(const f16x8*)(Al + lrow * lda + kt * 32 + lk8);
        acc = MFMA(ah, bh[kt], acc);
        pe  = MFMA(ah, bl[kt], pe);
        qe  = MFMA(al, bh[kt], qe);
    }
    return acc + (pe + qe) * INV;
}

__global__ __launch_bounds__(512, 1) void odernn_mfma(
    const float* __restrict__ x2d, const int* __restrict__ maskp,
    const _Float16* __restrict__ w0h, const _Float16* __restrict__ w0l,
    const _Float16* __restrict__ w1hg, const _Float16* __restrict__ w1lg,
    const _Float16* __restrict__ w2h, const _Float16* __restrict__ w2l,
    const _Float16* __restrict__ hh0h, const _Float16* __restrict__ hh0l,
    const _Float16* __restrict__ ih1h, const _Float16* __restrict__ ih1l,
    const _Float16* __restrict__ hh1h, const _Float16* __restrict__ hh1l,
    const float* __restrict__ b0, const float* __restrict__ b1,
    const float* __restrict__ b2, const float* __restrict__ bhh0,
    const float* __restrict__ bih0, const float* __restrict__ wih0,
    const float* __restrict__ bih1, const float* __restrict__ bhh1,
    const float* __restrict__ wout, const float* __restrict__ bout,
    const float* __restrict__ h0, float* __restrict__ out)
{
    __shared__ float hF[NRB][128];                      // fp32 master hidden state
    __shared__ _Float16 bAh[16][264], bAl[16][264];     // t2 (256-wide) hi/lo
    __shared__ _Float16 bBh[16][264], bBl[16][264];     // t1 / h2 hi/lo
    __shared__ _Float16 bHh[16][136], bHl[16][136];     // current h / h1 hi/lo
    __shared__ float sbias[NBIAS];
    __shared__ float swi0[768];
    __shared__ float swout[384];
    __shared__ float sbout[4];
    __shared__ float sx0[NRB], sx1[NRB], smm[NRB];
    __shared__ int sIdx[NRB];

    const int tid = (int)threadIdx.x;
    const int wv = tid >> 6;            // wave 0..7
    const int l = tid & 63;
    const int lrow = l & 15;            // A-row / D-col within tile
    const int lk8 = (l >> 4) << 3;      // k-octet within 32-wide k-tile
    const int rbase = (l >> 4) << 2;    // D-row base for this lane

    // ---- LDS init ----
    for (int e = tid; e < 256; e += 512) { sbias[OB0 + e] = b0[e]; sbias[OB1 + e] = b1[e]; }
    for (int e = tid; e < 128; e += 512) sbias[OB2 + e] = b2[e];
    for (int e = tid; e < 384; e += 512) {
        sbias[OBHH0 + e] = bhh0[e];
        sbias[OBIH0 + e] = bih0[e];
        sbias[OBIH1 + e] = bih1[e];
        sbias[OBHH1 + e] = bhh1[e];
        swout[e] = wout[e];
    }
    for (int e = tid; e < 768; e += 512) swi0[e] = wih0[e];
    if (tid < 3) sbout[tid] = bout[tid];
    // zero-init A buffers (dummy rows 4-15 stay finite forever)
    for (int e = tid; e < 16 * 264; e += 512) {
        bAh[0][e] = (_Float16)0.f; bAl[0][e] = (_Float16)0.f;
        bBh[0][e] = (_Float16)0.f; bBl[0][e] = (_Float16)0.f;
    }
    for (int e = tid; e < 16 * 136; e += 512) {
        int row = e / 136, col = e - row * 136;
        float v = (col < 128) ? h0[col] : 0.f;
        _Float16 hh = (_Float16)v;
        bHh[0][e] = hh;
        bHl[0][e] = (_Float16)((v - (float)hh) * LS);
    }
    for (int e = tid; e < NRB * 128; e += 512) hF[e >> 7][e & 127] = h0[e & 127];
    if (tid < NRB) {
        int grow = (int)blockIdx.x * NRB + tid;
        int bb = grow / 34, nn = grow - bb * 34;
        sIdx[tid] = bb * (S_ * 34) + nn;
    }
    __syncthreads();

    for (int s = 0; s < S_; ++s) {
        // x/mask for this step (consumed at P5, several barriers later)
        if (tid < NRB) {
            int idx = sIdx[tid] + s * 34;
            float fm = (float)maskp[idx];
            smm[tid] = fm;
            sx0[tid] = x2d[2 * idx] * fm;
            sx1[tid] = x2d[2 * idx + 1] * fm;
        }

        // ================= 4 Euler steps =================
        for (int it = 0; it < 4; ++it) {
            // P1: t1 = tanh(h @ w0 + b0) -> bufB   (K=128 KT=4, 2 tiles/wave)
            {
                f32x4 v0 = tile_mm<4>(w0h, w0l, wv, &bHh[0][0], &bHl[0][0], 136,
                                      l, lrow, lk8, sbias[OB0 + (wv << 4) + lrow]);
                f32x4 v1 = tile_mm<4>(w0h, w0l, wv + 8, &bHh[0][0], &bHl[0][0], 136,
                                      l, lrow, lk8, sbias[OB0 + ((wv + 8) << 4) + lrow]);
                const int n0 = wv << 4, n1 = (wv + 8) << 4;
#pragma unroll
                for (int r = 0; r < 4; ++r) {
                    int row = rbase + r;
                    if (row < NRB) {
                        float t0 = fast_tanh(v0[r]);
                        float t1 = fast_tanh(v1[r]);
                        _Float16 hh = (_Float16)t0;
                        bBh[row][n0 + lrow] = hh;
                        bBl[row][n0 + lrow] = (_Float16)((t0 - (float)hh) * LS);
                        hh = (_Float16)t1;
                        bBh[row][n1 + lrow] = hh;
                        bBl[row][n1 + lrow] = (_Float16)((t1 - (float)hh) * LS);
                    }
                }
            }
            __syncthreads();

            // P2: t2 = tanh(t1 @ w1 + b1) -> bufA  (K=256 KT=8, 2 tiles/wave)
            {
                f32x4 v0 = tile_mm<8>(w1hg, w1lg, wv, &bBh[0][0], &bBl[0][0], 264,
                                      l, lrow, lk8, sbias[OB1 + (wv << 4) + lrow]);
                f32x4 v1 = tile_mm<8>(w1hg, w1lg, wv + 8, &bBh[0][0], &bBl[0][0], 264,
                                      l, lrow, lk8, sbias[OB1 + ((wv + 8) << 4) + lrow]);
                const int n0 = wv << 4, n1 = (wv + 8) << 4;
#pragma unroll
                for (int r = 0; r < 4; ++r) {
                    int row = rbase + r;
                    if (row < NRB) {
                        float t0 = fast_tanh(v0[r]);
                        float t1 = fast_tanh(v1[r]);
                        _Float16 hh = (_Float16)t0;
                        bAh[row][n0 + lrow] = hh;
                        bAl[row][n0 + lrow] = (_Float16)((t0 - (float)hh) * LS);
                        hh = (_Float16)t1;
                        bAh[row][n1 + lrow] = hh;
                        bAl[row][n1 + lrow] = (_Float16)((t1 - (float)hh) * LS);
                    }
                }
            }
            __syncthreads();

            // P3: f = t2 @ w2 + b2 ; hF += DT*f ; cast new h -> bufH  (KT=8, 1 tile/wave)
            {
                f32x4 f = tile_mm<8>(w2h, w2l, wv, &bAh[0][0], &bAl[0][0], 264,
                                     l, lrow, lk8, sbias[OB2 + (wv << 4) + lrow]);
#pragma unroll
                for (int r = 0; r < 4; ++r) {
                    int row = rbase + r;
                    if (row < NRB) {
                        int col = (wv << 4) + lrow;
                        float v = hF[row][col] + DT_ * f[r];
                        hF[row][col] = v;
                        _Float16 hh = (_Float16)v;
                        bHh[row][col] = hh;
                        bHl[row][col] = (_Float16)((v - (float)hh) * LS);
                    }
                }
            }
            __syncthreads();
        }

        // P5: gh0 = h1 @ whh0 + bhh0 (3 tiles/wave) ; y-out ; GRU0 combine -> bufB
        {
            f32x4 gh[3];
#pragma unroll
            for (int t = 0; t < 3; ++t)
                gh[t] = tile_mm<4>(hh0h, hh0l, wv + (t << 3), &bHh[0][0], &bHl[0][0], 136,
                                   l, lrow, lk8, sbias[OBHH0 + ((wv + (t << 3)) << 4) + lrow]);
            // y = h1 @ wout + bout  (lanes 0-31: row wv ; lanes 32-63: row wv+8)
            {
                int yrow = wv + ((l >> 5) << 3);
                int ll = l & 31;
                int c0 = ll << 2;
                float4 hv;
                if (yrow < NRB) hv = *(const float4*)&hF[yrow][c0];
                else hv = make_float4(0.f, 0.f, 0.f, 0.f);
                float y0 = hv.x * swout[c0 * 3] + hv.y * swout[(c0 + 1) * 3] +
                           hv.z * swout[(c0 + 2) * 3] + hv.w * swout[(c0 + 3) * 3];
                float y1 = hv.x * swout[c0 * 3 + 1] + hv.y * swout[(c0 + 1) * 3 + 1] +
                           hv.z * swout[(c0 + 2) * 3 + 1] + hv.w * swout[(c0 + 3) * 3 + 1];
                float y2 = hv.x * swout[c0 * 3 + 2] + hv.y * swout[(c0 + 1) * 3 + 2] +
                           hv.z * swout[(c0 + 2) * 3 + 2] + hv.w * swout[(c0 + 3) * 3 + 2];
#pragma unroll
                for (int m = 16; m >= 1; m >>= 1) {
                    y0 += __shfl_xor(y0, m, 64);
                    y1 += __shfl_xor(y1, m, 64);
                    y2 += __shfl_xor(y2, m, 64);
                }
                if (ll == 0 && yrow < NRB) {
                    int idx = sIdx[yrow] + s * 34;
                    out[idx * 3 + 0] = y0 + sbout[0];
                    out[idx * 3 + 1] = y1 + sbout[1];
                    out[idx * 3 + 2] = y2 + sbout[2];
                }
            }
            // GRU0 combine: h2 -> bufB cols 0..127
            {
                int col = (wv << 4) + lrow;
                float wxr0 = swi0[col], wxr1 = swi0[384 + col];
                float wxz0 = swi0[128 + col], wxz1 = swi0[384 + 128 + col];
                float wxn0 = swi0[256 + col], wxn1 = swi0[384 + 256 + col];
                float bir = sbias[OBIH0 + col], biz = sbias[OBIH0 + 128 + col], bin = sbias[OBIH0 + 256 + col];
#pragma unroll
                for (int r = 0; r < 4; ++r) {
                    int row = rbase + r;
                    if (row < NRB) {
                        float xa = sx0[row], xb = sx1[row];
                        float rg = fast_sigmoid(bir + xa * wxr0 + xb * wxr1 + gh[0][r]);
                        float zg = fast_sigmoid(biz + xa * wxz0 + xb * wxz1 + gh[1][r]);
                        float nn = fast_tanh(bin + xa * wxn0 + xb * wxn1 + rg * gh[2][r]);
                        float h1 = hF[row][col];
                        float h2 = (1.0f - zg) * nn + zg * h1;
                        _Float16 hh = (_Float16)h2;
                        bBh[row][col] = hh;
                        bBl[row][col] = (_Float16)((h2 - (float)hh) * LS);
                    }
                }
            }
        }
        __syncthreads();

        // P7: gi1 = h2 @ wih1 + bih1 ; gh1 = h1 @ whh1 + bhh1 ; GRU1 combine -> hF + bufH
        {
            f32x4 gi[3], gh[3];
#pragma unroll
            for (int t = 0; t < 3; ++t)
                gi[t] = tile_mm<4>(ih1h, ih1l, wv + (t << 3), &bBh[0][0], &bBl[0][0], 264,
                                   l, lrow, lk8, sbias[OBIH1 + ((wv + (t << 3)) << 4) + lrow]);
#pragma unroll
            for (int t = 0; t < 3; ++t)
                gh[t] = tile_mm<4>(hh1h, hh1l, wv + (t << 3), &bHh[0][0], &bHl[0][0], 136,
                                   l, lrow, lk8, sbias[OBHH1 + ((wv + (t << 3)) << 4) + lrow]);

            __syncthreads();   // all reads of bHh/bHl/bBh for this step are done
#pragma unroll
            for (int r = 0; r < 4; ++r) {
                int row = rbase + r;
                if (row < NRB) {
                    int col = (wv << 4) + lrow;
                    float rg = fast_sigmoid(gi[0][r] + gh[0][r]);
                    float zg = fast_sigmoid(gi[1][r] + gh[1][r]);
                    float nn = fast_tanh(gi[2][r] + rg * gh[2][r]);
                    float h1 = hF[row][col];
                    float h2 = (1.0f - zg) * nn + zg * h1;
                    float v = (smm[row] != 0.0f) ? h2 : h1;
                    hF[row][col] = v;
                    _Float16 hh = (_Float16)v;
                    bHh[row][col] = hh;
                    bHl[row][col] = (_Float16)((v - (float)hh) * LS);
                }
            }
        }
        __syncthreads();
    }
}

extern "C" void kernel_launch(void* const* d_in, const int* in_sizes, int n_in,
                              void* d_out, int out_size, void* d_ws, size_t ws_size,
                              hipStream_t stream) {
    const float* x2d  = (const float*)d_in[0];
    const int*   mask = (const int*)d_in[1];
    const float* w0   = (const float*)d_in[2];
    const float* b0   = (const float*)d_in[3];
    const float* w1   = (const float*)d_in[4];
    const float* b1   = (const float*)d_in[5];
    const float* w2   = (const float*)d_in[6];
    const float* b2   = (const float*)d_in[7];
    const float* wih0 = (const float*)d_in[8];
    const float* whh0 = (const float*)d_in[9];
    const float* bih0 = (const float*)d_in[10];
    const float* bhh0 = (const float*)d_in[11];
    const float* wih1 = (const float*)d_in[12];
    const float* whh1 = (const float*)d_in[13];
    const float* bih1 = (const float*)d_in[14];
    const float* bhh1 = (const float*)d_in[15];
    const float* wout = (const float*)d_in[16];
    const float* bout = (const float*)d_in[17];
    const float* h0   = (const float*)d_in[18];
    float* out = (float*)d_out;

    _Float16* base = (_Float16*)d_ws;
    _Float16* pw0h  = base;                 // 32768
    _Float16* pw1h  = base + 32768;         // 65536
    _Float16* pw2h  = base + 98304;         // 32768
    _Float16* ph0h  = base + 131072;        // 49152 (whh0)
    _Float16* pi1h  = base + 180224;        // 49152 (wih1)
    _Float16* ph1h  = base + 229376;        // 49152 (whh1)
    _Float16* lobase = base + 278528;
    _Float16* pw0l  = lobase;
    _Float16* pw1l  = lobase + 32768;
    _Float16* pw2l  = lobase + 98304;
    _Float16* ph0l  = lobase + 131072;
    _Float16* pi1l  = lobase + 180224;
    _Float16* ph1l  = lobase + 229376;

    hipLaunchKernelGGL(prep_hl, dim3(128), dim3(256), 0, stream, w0,   pw0h, pw0l, 128, 256);
    hipLaunchKernelGGL(prep_hl, dim3(256), dim3(256), 0, stream, w1,   pw1h, pw1l, 256, 256);
    hipLaunchKernelGGL(prep_hl, dim3(128), dim3(256), 0, stream, w2,   pw2h, pw2l, 256, 128);
    hipLaunchKernelGGL(prep_hl, dim3(192), dim3(256), 0, stream, whh0, ph0h, ph0l, 128, 384);
    hipLaunchKernelGGL(prep_hl, dim3(192), dim3(256), 0, stream, wih1, pi1h, pi1l, 128, 384);
    hipLaunchKernelGGL(prep_hl, dim3(192), dim3(256), 0, stream, whh1, ph1h, ph1l, 128, 384);

    hipLaunchKernelGGL(odernn_mfma, dim3(272), dim3(512), 0, stream,
        x2d, mask, pw0h, pw0l, pw1h, pw1l, pw2h, pw2l,
        ph0h, ph0l, pi1h, pi1l, ph1h, ph1l,
        b0, b1, b2, bhh0, bih0, wih0, bih1, bhh1, wout, bout, h0, out);
}

// Round 11
// 7286.789 us; speedup vs baseline: 2.2780x; 2.2780x over previous
//
#include <hip/hip_runtime.h>

typedef _Float16 f16x8 __attribute__((ext_vector_type(8)));
typedef float f32x4 __attribute__((ext_vector_type(4)));

constexpr int S_ = 128;
constexpr float DT_ = 0.1f;
constexpr float LS = 2048.0f;          // lo-term scale (2^11) keeps fp16 lo parts normal
constexpr float INV = 1.0f / 2048.0f;

#define MFMA(a, b, c) __builtin_amdgcn_mfma_f32_16x16x32_f16((a), (b), (c), 0, 0, 0)
#define SB() __builtin_amdgcn_sched_barrier(0)

// bias LDS offsets (floats)
#define OB0   0
#define OB1   256
#define OB2   512
#define OBHH0 640
#define OBIH0 1024
#define OBIH1 1408
#define OBHH1 1792
#define NBIAS 2176

__device__ __forceinline__ float fast_tanh(float x) {
    float e = __expf(2.0f * x);
    return 1.0f - 2.0f / (e + 1.0f);
}
__device__ __forceinline__ float fast_sigmoid(float x) {
    return 1.0f / (1.0f + __expf(-x));
}
__device__ __forceinline__ f32x4 bc4(float v) { return (f32x4){v, v, v, v}; }

// async global->LDS, 16B per lane; LDS dest = wave-uniform base + lane*16
__device__ __forceinline__ void gld16(const _Float16* g, _Float16* l) {
    __builtin_amdgcn_global_load_lds(
        (const __attribute__((address_space(1))) void*)g,
        (__attribute__((address_space(3))) void*)l, 16, 0, 0);
}
template<int N> __device__ __forceinline__ void waitvm() {
    if constexpr (N == 0) asm volatile("s_waitcnt vmcnt(0)" ::: "memory");
    else if constexpr (N == 2) asm volatile("s_waitcnt vmcnt(2)" ::: "memory");
    else if constexpr (N == 4) asm volatile("s_waitcnt vmcnt(4)" ::: "memory");
    SB();
}

// fp32 row-major KxN -> fp16 hi/lo MFMA-B-fragment blobs.
// Tile (nt,kt) at ((nt*KT)+kt)*512; elem lane*8+j <-> B[kt*32+(lane>>4)*8+j][nt*16+(lane&15)].
__global__ void prep_hl(const float* __restrict__ src, _Float16* __restrict__ hi,
                        _Float16* __restrict__ lo, int K, int N) {
    int e = blockIdx.x * 256 + threadIdx.x;
    if (e >= K * N) return;
    int tile = e >> 9, r = e & 511;
    int lane = r >> 3, j = r & 7;
    int KT = K >> 5;
    int nt = tile / KT, kt = tile - nt * KT;
    int k = kt * 32 + ((lane >> 4) << 3) + j;
    int n = nt * 16 + (lane & 15);
    float v = src[k * N + n];
    _Float16 h = (_Float16)v;
    hi[e] = h;
    lo[e] = (_Float16)((v - (float)h) * LS);
}

// One matvec phase, slice-double-buffered through wave-private LDS staging.
// Entry drains vmcnt (counted waits must be exact; stray x/mask loads and
// y-stores pollute vmcnt otherwise).  SB() before each gld16 batch pins the
// WAR order: iteration kt's ds_reads of buf(kt&1) are provably consumed
// (MFMA issued => lgkm wait satisfied) before iteration kt+1's DMA overwrite
// of that same buffer can issue.
template<int KT, int NTW>
__device__ __forceinline__ void mm_phase(
    const _Float16* __restrict__ Wh, const _Float16* __restrict__ Wl,
    const int* nts,
    const _Float16* __restrict__ Ah, const _Float16* __restrict__ Al, int lda,
    _Float16* wbase, int l, int lrow, int lk8,
    f32x4* acc, f32x4* pe, f32x4* qe)
{
    waitvm<0>();                     // exact-count baseline
    const int lb = l * 8;            // lane's 16B offset (in f16 units)
    // prologue: stage slice 0 into buf0
#pragma unroll
    for (int t = 0; t < NTW; ++t) {
        gld16(Wh + ((size_t)nts[t] * KT) * 512 + lb, wbase + (2 * t) * 512);
        gld16(Wl + ((size_t)nts[t] * KT) * 512 + lb, wbase + (2 * t + 1) * 512);
    }
#pragma unroll
    for (int kt = 0; kt < KT; ++kt) {
        _Float16* cb = wbase + (kt & 1) * 2048;
        if (kt + 1 < KT) {
            SB();                    // prior ds_reads/MFMAs must stay above this point
            _Float16* nb = wbase + ((kt + 1) & 1) * 2048;
#pragma unroll
            for (int t = 0; t < NTW; ++t) {
                gld16(Wh + ((size_t)(nts[t] * KT + kt + 1)) * 512 + lb, nb + (2 * t) * 512);
                gld16(Wl + ((size_t)(nts[t] * KT + kt + 1)) * 512 + lb, nb + (2 * t + 1) * 512);
            }
            waitvm<2 * NTW>();       // slice kt complete; slice kt+1 stays in flight
        } else {
            waitvm<0>();
        }
        f16x8 ah = *(const f16x8*)(Ah + lrow * lda + kt * 32 + lk8);
        f16x8 al = *(const f16x8*)(Al + lrow * lda + kt * 32 + lk8);
#pragma unroll
        for (int t = 0; t < NTW; ++t) {
            f16x8 bh = *(const f16x8*)(cb + (2 * t) * 512 + lb);
            f16x8 bl = *(const f16x8*)(cb + (2 * t + 1) * 512 + lb);
            acc[t] = MFMA(ah, bh, acc[t]);
            pe[t]  = MFMA(ah, bl, pe[t]);
            qe[t]  = MFMA(al, bh, qe[t]);
        }
    }
}

__global__ __launch_bounds__(512, 1) void odernn_mfma(
    const float* __restrict__ x2d, const int* __restrict__ maskp,
    const _Float16* __restrict__ w0h, const _Float16* __restrict__ w0l,
    const _Float16* __restrict__ w1hg, const _Float16* __restrict__ w1lg,
    const _Float16* __restrict__ w2h, const _Float16* __restrict__ w2l,
    const _Float16* __restrict__ hh0h, const _Float16* __restrict__ hh0l,
    const _Float16* __restrict__ ih1h, const _Float16* __restrict__ ih1l,
    const _Float16* __restrict__ hh1h, const _Float16* __restrict__ hh1l,
    const float* __restrict__ b0, const float* __restrict__ b1,
    const float* __restrict__ b2, const float* __restrict__ bhh0,
    const float* __restrict__ bih0, const float* __restrict__ wih0,
    const float* __restrict__ bih1, const float* __restrict__ bhh1,
    const float* __restrict__ wout, const float* __restrict__ bout,
    const float* __restrict__ h0, float* __restrict__ out)
{
    __shared__ float hF[16][128];                       // fp32 master hidden state
    __shared__ _Float16 bAh[16][264], bAl[16][264];     // t2 (256-wide) hi/lo
    __shared__ _Float16 bBh[16][264], bBl[16][264];     // t1 / h2 hi/lo
    __shared__ _Float16 bHh[16][136], bHl[16][136];     // current h / h1 hi/lo
    __shared__ _Float16 wstage[8][2][4][512];           // weight stage: wave x dbuf x chunks (64KB)
    __shared__ float sbias[NBIAS];
    __shared__ float swi0[768];
    __shared__ float swout[384];
    __shared__ float sbout[4];
    __shared__ float sx0[16], sx1[16], smm[16];
    __shared__ int sIdx[16];

    const int tid = (int)threadIdx.x;
    const int wv = tid >> 6;            // wave 0..7
    const int l = tid & 63;
    const int lrow = l & 15;            // A-row / D-col within tile
    const int lk8 = (l >> 4) << 3;      // k-octet within 32-wide k-tile
    const int rbase = (l >> 4) << 2;    // D-row base for this lane
    _Float16* wb = &wstage[wv][0][0][0];

    // ---- LDS init ----
    for (int e = tid; e < 256; e += 512) { sbias[OB0 + e] = b0[e]; sbias[OB1 + e] = b1[e]; }
    for (int e = tid; e < 128; e += 512) sbias[OB2 + e] = b2[e];
    for (int e = tid; e < 384; e += 512) {
        sbias[OBHH0 + e] = bhh0[e];
        sbias[OBIH0 + e] = bih0[e];
        sbias[OBIH1 + e] = bih1[e];
        sbias[OBHH1 + e] = bhh1[e];
        swout[e] = wout[e];
    }
    for (int e = tid; e < 768; e += 512) swi0[e] = wih0[e];
    if (tid < 3) sbout[tid] = bout[tid];
    for (int e = tid; e < 2048; e += 512) {
        int row = e >> 7, col = e & 127;
        float v = h0[col];
        hF[row][col] = v;
        _Float16 hh = (_Float16)v;
        bHh[row][col] = hh;
        bHl[row][col] = (_Float16)((v - (float)hh) * LS);
    }
    if (tid < 16) {
        int grow = (int)blockIdx.x * 16 + tid;
        int bb = grow / 34, nn = grow - bb * 34;
        sIdx[tid] = bb * (S_ * 34) + nn;
    }
    __syncthreads();

    const int nts01[2] = {wv, wv + 8};
    const int nts2[1] = {wv + 16};
    const int ntsw[1] = {wv};

    for (int s = 0; s < S_; ++s) {
        // x/mask for this step (consumed at P5; P1's phase-entry drain covers these)
        if (tid < 16) {
            int idx = sIdx[tid] + s * 34;
            float fm = (float)maskp[idx];
            smm[tid] = fm;
            sx0[tid] = x2d[2 * idx] * fm;
            sx1[tid] = x2d[2 * idx + 1] * fm;
        }

        // ================= 4 Euler steps =================
        for (int it = 0; it < 4; ++it) {
            // P1: t1 = tanh(h @ w0 + b0) -> bufB   (K=128 KT=4, 2 tiles/wave)
            {
                f32x4 acc[2] = {bc4(sbias[OB0 + (wv << 4) + lrow]),
                                bc4(sbias[OB0 + ((wv + 8) << 4) + lrow])};
                f32x4 pe[2] = {bc4(0.f), bc4(0.f)}, qe[2] = {bc4(0.f), bc4(0.f)};
                mm_phase<4, 2>(w0h, w0l, nts01, &bHh[0][0], &bHl[0][0], 136,
                               wb, l, lrow, lk8, acc, pe, qe);
                const int n0 = wv << 4, n1 = (wv + 8) << 4;
#pragma unroll
                for (int r = 0; r < 4; ++r) {
                    int row = rbase + r;
                    float v0 = fast_tanh(acc[0][r] + (pe[0][r] + qe[0][r]) * INV);
                    float v1 = fast_tanh(acc[1][r] + (pe[1][r] + qe[1][r]) * INV);
                    _Float16 hh = (_Float16)v0;
                    bBh[row][n0 + lrow] = hh;
                    bBl[row][n0 + lrow] = (_Float16)((v0 - (float)hh) * LS);
                    hh = (_Float16)v1;
                    bBh[row][n1 + lrow] = hh;
                    bBl[row][n1 + lrow] = (_Float16)((v1 - (float)hh) * LS);
                }
            }
            __syncthreads();

            // P2: t2 = tanh(t1 @ w1 + b1) -> bufA  (K=256 KT=8, 2 tiles/wave)
            {
                f32x4 acc[2] = {bc4(sbias[OB1 + (wv << 4) + lrow]),
                                bc4(sbias[OB1 + ((wv + 8) << 4) + lrow])};
                f32x4 pe[2] = {bc4(0.f), bc4(0.f)}, qe[2] = {bc4(0.f), bc4(0.f)};
                mm_phase<8, 2>(w1hg, w1lg, nts01, &bBh[0][0], &bBl[0][0], 264,
                               wb, l, lrow, lk8, acc, pe, qe);
                const int n0 = wv << 4, n1 = (wv + 8) << 4;
#pragma unroll
                for (int r = 0; r < 4; ++r) {
                    int row = rbase + r;
                    float v0 = fast_tanh(acc[0][r] + (pe[0][r] + qe[0][r]) * INV);
                    float v1 = fast_tanh(acc[1][r] + (pe[1][r] + qe[1][r]) * INV);
                    _Float16 hh = (_Float16)v0;
                    bAh[row][n0 + lrow] = hh;
                    bAl[row][n0 + lrow] = (_Float16)((v0 - (float)hh) * LS);
                    hh = (_Float16)v1;
                    bAh[row][n1 + lrow] = hh;
                    bAl[row][n1 + lrow] = (_Float16)((v1 - (float)hh) * LS);
                }
            }
            __syncthreads();

            // P3: f = t2 @ w2 + b2 ; hF += DT*f ; cast new h -> bufH  (KT=8, 1 tile/wave)
            {
                f32x4 acc[1] = {bc4(sbias[OB2 + (wv << 4) + lrow])};
                f32x4 pe[1] = {bc4(0.f)}, qe[1] = {bc4(0.f)};
                mm_phase<8, 1>(w2h, w2l, ntsw, &bAh[0][0], &bAl[0][0], 264,
                               wb, l, lrow, lk8, acc, pe, qe);
#pragma unroll
                for (int r = 0; r < 4; ++r) {
                    int row = rbase + r, col = (wv << 4) + lrow;
                    float v = hF[row][col] + DT_ * (acc[0][r] + (pe[0][r] + qe[0][r]) * INV);
                    hF[row][col] = v;
                    _Float16 hh = (_Float16)v;
                    bHh[row][col] = hh;
                    bHl[row][col] = (_Float16)((v - (float)hh) * LS);
                }
            }
            __syncthreads();
        }

        // P5: gh0 = h1 @ whh0 + bhh0 (3 tiles/wave: 2+1) ; y-out ; GRU0 combine -> bufB
        {
            f32x4 acc[3] = {bc4(sbias[OBHH0 + (wv << 4) + lrow]),
                            bc4(sbias[OBHH0 + ((wv + 8) << 4) + lrow]),
                            bc4(sbias[OBHH0 + ((wv + 16) << 4) + lrow])};
            f32x4 pe[3] = {bc4(0.f), bc4(0.f), bc4(0.f)};
            f32x4 qe[3] = {bc4(0.f), bc4(0.f), bc4(0.f)};
            mm_phase<4, 2>(hh0h, hh0l, nts01, &bHh[0][0], &bHl[0][0], 136,
                           wb, l, lrow, lk8, acc, pe, qe);
            mm_phase<4, 1>(hh0h, hh0l, nts2, &bHh[0][0], &bHl[0][0], 136,
                           wb, l, lrow, lk8, acc + 2, pe + 2, qe + 2);
            // y = h1 @ wout + bout  (lanes 0-31: row wv ; lanes 32-63: row wv+8)
            {
                int yrow = wv + ((l >> 5) << 3);
                int ll = l & 31;
                int c0 = ll << 2;
                float4 hv = *(const float4*)&hF[yrow][c0];
                float y0 = hv.x * swout[c0 * 3] + hv.y * swout[(c0 + 1) * 3] +
                           hv.z * swout[(c0 + 2) * 3] + hv.w * swout[(c0 + 3) * 3];
                float y1 = hv.x * swout[c0 * 3 + 1] + hv.y * swout[(c0 + 1) * 3 + 1] +
                           hv.z * swout[(c0 + 2) * 3 + 1] + hv.w * swout[(c0 + 3) * 3 + 1];
                float y2 = hv.x * swout[c0 * 3 + 2] + hv.y * swout[(c0 + 1) * 3 + 2] +
                           hv.z * swout[(c0 + 2) * 3 + 2] + hv.w * swout[(c0 + 3) * 3 + 2];
#pragma unroll
                for (int m = 16; m >= 1; m >>= 1) {
                    y0 += __shfl_xor(y0, m, 64);
                    y1 += __shfl_xor(y1, m, 64);
                    y2 += __shfl_xor(y2, m, 64);
                }
                if (ll == 0) {
                    int idx = sIdx[yrow] + s * 34;
                    out[idx * 3 + 0] = y0 + sbout[0];
                    out[idx * 3 + 1] = y1 + sbout[1];
                    out[idx * 3 + 2] = y2 + sbout[2];
                }
            }
            // GRU0 combine: h2 -> bufB cols 0..127
            {
                int col = (wv << 4) + lrow;
                float wxr0 = swi0[col], wxr1 = swi0[384 + col];
                float wxz0 = swi0[128 + col], wxz1 = swi0[384 + 128 + col];
                float wxn0 = swi0[256 + col], wxn1 = swi0[384 + 256 + col];
                float bir = sbias[OBIH0 + col], biz = sbias[OBIH0 + 128 + col], bin = sbias[OBIH0 + 256 + col];
#pragma unroll
                for (int r = 0; r < 4; ++r) {
                    int row = rbase + r;
                    float xa = sx0[row], xb = sx1[row];
                    float rg = fast_sigmoid(bir + xa * wxr0 + xb * wxr1 + acc[0][r] + (pe[0][r] + qe[0][r]) * INV);
                    float zg = fast_sigmoid(biz + xa * wxz0 + xb * wxz1 + acc[1][r] + (pe[1][r] + qe[1][r]) * INV);
                    float gn = acc[2][r] + (pe[2][r] + qe[2][r]) * INV;
                    float nn = fast_tanh(bin + xa * wxn0 + xb * wxn1 + rg * gn);
                    float h1 = hF[row][col];
                    float h2 = (1.0f - zg) * nn + zg * h1;
                    _Float16 hh = (_Float16)h2;
                    bBh[row][col] = hh;
                    bBl[row][col] = (_Float16)((h2 - (float)hh) * LS);
                }
            }
        }
        __syncthreads();

        // P7: gi1 = h2 @ wih1 + bih1 ; gh1 = h1 @ whh1 + bhh1 ; GRU1 combine -> hF + bufH
        {
            f32x4 aI[3] = {bc4(sbias[OBIH1 + (wv << 4) + lrow]),
                           bc4(sbias[OBIH1 + ((wv + 8) << 4) + lrow]),
                           bc4(sbias[OBIH1 + ((wv + 16) << 4) + lrow])};
            f32x4 pI[3] = {bc4(0.f), bc4(0.f), bc4(0.f)};
            f32x4 qI[3] = {bc4(0.f), bc4(0.f), bc4(0.f)};
            mm_phase<4, 2>(ih1h, ih1l, nts01, &bBh[0][0], &bBl[0][0], 264,
                           wb, l, lrow, lk8, aI, pI, qI);
            mm_phase<4, 1>(ih1h, ih1l, nts2, &bBh[0][0], &bBl[0][0], 264,
                           wb, l, lrow, lk8, aI + 2, pI + 2, qI + 2);
            f32x4 gi0 = aI[0] + (pI[0] + qI[0]) * INV;
            f32x4 gi1 = aI[1] + (pI[1] + qI[1]) * INV;
            f32x4 gi2 = aI[2] + (pI[2] + qI[2]) * INV;

            f32x4 aH[3] = {bc4(sbias[OBHH1 + (wv << 4) + lrow]),
                           bc4(sbias[OBHH1 + ((wv + 8) << 4) + lrow]),
                           bc4(sbias[OBHH1 + ((wv + 16) << 4) + lrow])};
            f32x4 pH[3] = {bc4(0.f), bc4(0.f), bc4(0.f)};
            f32x4 qH[3] = {bc4(0.f), bc4(0.f), bc4(0.f)};
            mm_phase<4, 2>(hh1h, hh1l, nts01, &bHh[0][0], &bHl[0][0], 136,
                           wb, l, lrow, lk8, aH, pH, qH);
            mm_phase<4, 1>(hh1h, hh1l, nts2, &bHh[0][0], &bHl[0][0], 136,
                           wb, l, lrow, lk8, aH + 2, pH + 2, qH + 2);

            __syncthreads();   // all reads of bHh/bHl/bBh for this step are done
#pragma unroll
            for (int r = 0; r < 4; ++r) {
                int row = rbase + r, col = (wv << 4) + lrow;
                float ghr = aH[0][r] + (pH[0][r] + qH[0][r]) * INV;
                float ghz = aH[1][r] + (pH[1][r] + qH[1][r]) * INV;
                float ghn = aH[2][r] + (pH[2][r] + qH[2][r]) * INV;
                float rg = fast_sigmoid(gi0[r] + ghr);
                float zg = fast_sigmoid(gi1[r] + ghz);
                float nn = fast_tanh(gi2[r] + rg * ghn);
                float h1 = hF[row][col];
                float h2 = (1.0f - zg) * nn + zg * h1;
                float v = (smm[row] != 0.0f) ? h2 : h1;
                hF[row][col] = v;
                _Float16 hh = (_Float16)v;
                bHh[row][col] = hh;
                bHl[row][col] = (_Float16)((v - (float)hh) * LS);
            }
        }
        __syncthreads();
    }
}

extern "C" void kernel_launch(void* const* d_in, const int* in_sizes, int n_in,
                              void* d_out, int out_size, void* d_ws, size_t ws_size,
                              hipStream_t stream) {
    const float* x2d  = (const float*)d_in[0];
    const int*   mask = (const int*)d_in[1];
    const float* w0   = (const float*)d_in[2];
    const float* b0   = (const float*)d_in[3];
    const float* w1   = (const float*)d_in[4];
    const float* b1   = (const float*)d_in[5];
    const float* w2   = (const float*)d_in[6];
    const float* b2   = (const float*)d_in[7];
    const float* wih0 = (const float*)d_in[8];
    const float* whh0 = (const float*)d_in[9];
    const float* bih0 = (const float*)d_in[10];
    const float* bhh0 = (const float*)d_in[11];
    const float* wih1 = (const float*)d_in[12];
    const float* whh1 = (const float*)d_in[13];
    const float* bih1 = (const float*)d_in[14];
    const float* bhh1 = (const float*)d_in[15];
    const float* wout = (const float*)d_in[16];
    const float* bout = (const float*)d_in[17];
    const float* h0   = (const float*)d_in[18];
    float* out = (float*)d_out;

    _Float16* base = (_Float16*)d_ws;
    _Float16* pw0h  = base;                 // 32768
    _Float16* pw1h  = base + 32768;         // 65536
    _Float16* pw2h  = base + 98304;         // 32768
    _Float16* ph0h  = base + 131072;        // 49152 (whh0)
    _Float16* pi1h  = base + 180224;        // 49152 (wih1)
    _Float16* ph1h  = base + 229376;        // 49152 (whh1)
    _Float16* lobase = base + 278528;
    _Float16* pw0l  = lobase;
    _Float16* pw1l  = lobase + 32768;
    _Float16* pw2l  = lobase + 98304;
    _Float16* ph0l  = lobase + 131072;
    _Float16* pi1l  = lobase + 180224;
    _Float16* ph1l  = lobase + 229376;

    hipLaunchKernelGGL(prep_hl, dim3(128), dim3(256), 0, stream, w0,   pw0h, pw0l, 128, 256);
    hipLaunchKernelGGL(prep_hl, dim3(256), dim3(256), 0, stream, w1,   pw1h, pw1l, 256, 256);
    hipLaunchKernelGGL(prep_hl, dim3(128), dim3(256), 0, stream, w2,   pw2h, pw2l, 256, 128);
    hipLaunchKernelGGL(prep_hl, dim3(192), dim3(256), 0, stream, whh0, ph0h, ph0l, 128, 384);
    hipLaunchKernelGGL(prep_hl, dim3(192), dim3(256), 0, stream, wih1, pi1h, pi1l, 128, 384);
    hipLaunchKernelGGL(prep_hl, dim3(192), dim3(256), 0, stream, whh1, ph1h, ph1l, 128, 384);

    hipLaunchKernelGGL(odernn_mfma, dim3(68), dim3(512), 0, stream,
        x2d, mask, pw0h, pw0l, pw1h, pw1l, pw2h, pw2l,
        ph0h, ph0l, pi1h, pi1l, ph1h, ph1l,
        b0, b1, b2, bhh0, bih0, wih0, bih1, bhh1, wout, bout, h0, out);
}